// Round 16
// baseline (260.446 us; speedup 1.0000x reference)
//
#include <hip/hip_runtime.h>

#define NN 384
#define DM 256
#define NH 4
#define FF 1024
#define HIDN 512
#define NCLS 56
#define NPAIR (NN*(NN-1))   // 147072
#define NBLK 48

typedef __attribute__((ext_vector_type(8))) short short8v;
typedef __attribute__((ext_vector_type(4))) float f32x4;
typedef __attribute__((ext_vector_type(16))) float f32x16;
typedef __attribute__((ext_vector_type(8))) unsigned short ushort8;
typedef __attribute__((ext_vector_type(4))) unsigned int uint4v;

static __device__ __forceinline__ unsigned short f2bf(float f) {
  unsigned u = __float_as_uint(f);
  unsigned r = u + 0x7fff + ((u >> 16) & 1);   // RNE
  return (unsigned short)(r >> 16);
}
static __device__ __forceinline__ float bf2f(unsigned short v) {
  return __uint_as_float(((unsigned)v) << 16);
}
static __device__ __forceinline__ unsigned cvt_pk_bf16(float lo, float hi) {
  unsigned r;
  asm("v_cvt_pk_bf16_f32 %0, %1, %2" : "=v"(r) : "v"(lo), "v"(hi));
  return r;
}
// C/D row for 32x32x16 MFMA (v7-verified): ml = (reg&3)+8*(reg>>2)+4*half
#define MLROW(reg, half) (((reg) & 3) + 8 * ((reg) >> 2) + 4 * (half))

// device-scope grid barrier: arrive (atomicAdd) + spin; fences for X-XCD vis.
static __device__ __forceinline__ void gsync(unsigned* bar, int ph) {
  __syncthreads();
  if (threadIdx.x == 0) {
    __threadfence();                       // release: flush my block's writes
    atomicAdd(bar + ph, 1u);
    while (atomicAdd(bar + ph, 0u) < (unsigned)NBLK)
      __builtin_amdgcn_s_sleep(1);
  }
  __syncthreads();
  __threadfence();                         // acquire: invalidate L1
}

template<int NKS, int NT>
static __device__ __forceinline__ f32x16 mfma_tile(const unsigned short* __restrict__ asrc,
                                                   const unsigned short* __restrict__ bsrc) {
  f32x16 acc = {};
  #pragma unroll
  for (int ks = 0; ks < NKS; ++ks) {
    short8v a = *reinterpret_cast<const short8v*>(asrc + ks * 16);
    short8v b = *reinterpret_cast<const short8v*>(bsrc + (size_t)ks * NT * 512);
    acc = __builtin_amdgcn_mfma_f32_32x32x16_bf16(a, b, acc, 0, 0, 0);
  }
  return acc;
}

// ===== persistent fused encoder: prep + 2 layers + UV, grid-barrier sync ===
__global__ __launch_bounds__(256)
void fused_enc(const float* __restrict__ node, const float* __restrict__ boxes,
               const float* __restrict__ w_in, const float* __restrict__ b_in,
               const float* __restrict__ w_out, const float* __restrict__ b_out,
               const float* __restrict__ fw1, const float* __restrict__ fb1,
               const float* __restrict__ fw2, const float* __restrict__ fb2,
               const float* __restrict__ ln1g, const float* __restrict__ ln1b,
               const float* __restrict__ ln2g, const float* __restrict__ ln2b,
               const float* __restrict__ mw1, const float* __restrict__ mb1,
               const float* __restrict__ mw2,
               float* __restrict__ xbuf, float* __restrict__ proj, float* __restrict__ U,
               unsigned short* __restrict__ x_bf, unsigned short* __restrict__ qk_bf,
               unsigned short* __restrict__ vt_bf, unsigned short* __restrict__ at_bf,
               unsigned short* __restrict__ ffh_bf, unsigned short* __restrict__ Vbf,
               unsigned short* __restrict__ wi_f, unsigned short* __restrict__ wo_f,
               unsigned short* __restrict__ fw1_f, unsigned short* __restrict__ fw2_f,
               unsigned short* __restrict__ mw1_f, unsigned short* __restrict__ w2_f,
               float* __restrict__ out, unsigned* __restrict__ bar) {
  __shared__ float S[32][385];
  __shared__ unsigned short P[32][392];
  int tid = threadIdx.x;
  int wave = tid >> 6, lane = tid & 63;
  int wid = blockIdx.x * 4 + wave;        // 0..191
  int col = lane & 31, half = lane >> 5;
  int gtid = blockIdx.x * 256 + tid;      // 0..12287
  int ph = 0;

  // ---- stage P: pack weights + x_init + pair indices ----
  for (int t0 = gtid; t0 < 233472; t0 += NBLK * 256) {
    int tt = t0; const float* src; unsigned short* dst; int N;
    if (tt < 49152)       { int z = tt / 24576; tt -= z * 24576; src = w_in  + (size_t)z * 196608; dst = wi_f  + (size_t)z * 196608; N = 768; }
    else if (tt < 65536)  { tt -= 49152;  int z = tt / 8192;  tt -= z * 8192;  src = w_out + (size_t)z * 65536;  dst = wo_f  + (size_t)z * 65536;  N = 256; }
    else if (tt < 131072) { tt -= 65536;  int z = tt / 32768; tt -= z * 32768; src = fw1   + (size_t)z * 262144; dst = fw1_f + (size_t)z * 262144; N = 1024; }
    else if (tt < 196608) { tt -= 131072; int z = tt / 32768; tt -= z * 32768; src = fw2   + (size_t)z * 262144; dst = fw2_f + (size_t)z * 262144; N = 256; }
    else if (tt < 229376) { tt -= 196608; int z = tt / 16384; tt -= z * 16384; src = mw1   + (size_t)z * 131072; dst = mw1_f + (size_t)z * 131072; N = 512; }
    else                  { tt -= 229376; src = mw2; dst = w2_f; N = 0; }
    int l = tt & 63, rem = tt >> 6;
    if (N) {
      int Nt = N >> 5;
      int nt = rem % Nt, ks = rem / Nt;
      int kb = ks * 16 + ((l >> 5) * 8), n = nt * 32 + (l & 31);
      #pragma unroll
      for (int r = 0; r < 8; ++r)
        dst[(size_t)tt * 8 + r] = f2bf(src[(size_t)(kb + r) * N + n]);
    } else {
      int nt = rem & 1, ks = rem >> 1;
      int kb = ks * 16 + ((l >> 5) * 8), n = nt * 32 + (l & 31);
      #pragma unroll
      for (int r = 0; r < 8; ++r) {
        float v = (n < NCLS) ? mw2[(size_t)(kb + r) * NCLS + n] : 0.f;
        dst[(size_t)tt * 8 + r] = f2bf(v);
      }
    }
  }
  for (int t = gtid; t < 24576; t += NBLK * 256) {
    float4 v = reinterpret_cast<const float4*>(node)[t];
    reinterpret_cast<float4*>(xbuf)[t] = v;
    uint2 pk;
    pk.x = cvt_pk_bf16(v.x, v.y);
    pk.y = cvt_pk_bf16(v.z, v.w);
    *reinterpret_cast<uint2*>(x_bf + (size_t)t * 4) = pk;
  }
  for (int t = gtid; t < NPAIR; t += NBLK * 256) {
    int i = t / (NN - 1);
    int r = t - i * (NN - 1);
    int j = r + (r >= i ? 1 : 0);
    out[2 * t + 0] = (float)i;
    out[2 * t + 1] = (float)j;
  }
  gsync(bar, ph++);

  for (int l = 0; l < 2; ++l) {
    const unsigned short* wi_fl  = wi_f  + (size_t)l * 196608;
    const unsigned short* wo_fl  = wo_f  + (size_t)l * 65536;
    const unsigned short* fw1_fl = fw1_f + (size_t)l * 262144;
    const unsigned short* fw2_fl = fw2_f + (size_t)l * 262144;
    const float* bi = b_in + (size_t)l * 768;
    const float* bo = b_out + (size_t)l * 256;
    const float* b1l = fb1 + (size_t)l * 1024;
    const float* b2l = fb2 + (size_t)l * 256;

    // ---- stage Q: qkv = x @ wi + bi ; Q|K row-major, V transposed ----
    for (int t = wid; t < 288; t += 192) {
      int mt = t % 12, nt = t / 12;
      const unsigned short* asrc = x_bf + (size_t)(mt * 32 + col) * 256 + half * 8;
      const unsigned short* bsrc = wi_fl + ((size_t)nt * 64 + lane) * 8;
      f32x16 acc = mfma_tile<16, 24>(asrc, bsrc);
      int n = nt * 32 + col;
      float bb = bi[n];
      #pragma unroll
      for (int reg = 0; reg < 16; ++reg) {
        int row = mt * 32 + MLROW(reg, half);
        float v = acc[reg] + bb;
        if (n < 512) qk_bf[(size_t)row * 512 + n] = f2bf(v);
        else         vt_bf[(size_t)(n - 512) * 384 + row] = f2bf(v);
      }
    }
    gsync(bar, ph++);

    // ---- stage A: attention (one 32-row x head tile per block) ----
    {
      int n0 = (blockIdx.x % 12) * 32;
      int h = blockIdx.x / 12;
      {
        const unsigned short* asrc = qk_bf + (size_t)(n0 + col) * 512 + h * 64 + half * 8;
        #pragma unroll
        for (int jj = 0; jj < 3; ++jj) {
          int ntk = wave * 3 + jj;
          const unsigned short* bsrc = qk_bf + (size_t)(ntk * 32 + col) * 512 + 256 + h * 64 + half * 8;
          f32x16 acc = {};
          #pragma unroll
          for (int ks = 0; ks < 4; ++ks) {
            short8v a = *reinterpret_cast<const short8v*>(asrc + ks * 16);
            short8v b = *reinterpret_cast<const short8v*>(bsrc + ks * 16);
            acc = __builtin_amdgcn_mfma_f32_32x32x16_bf16(a, b, acc, 0, 0, 0);
          }
          #pragma unroll
          for (int reg = 0; reg < 16; ++reg)
            S[MLROW(reg, half)][ntk * 32 + col] = acc[reg] * 0.125f;
        }
      }
      __syncthreads();
      {
        int row = tid >> 3, q = tid & 7;
        float mx = -1e30f;
        #pragma unroll 8
        for (int c = 0; c < 48; ++c) mx = fmaxf(mx, S[row][q * 48 + c]);
        mx = fmaxf(mx, __shfl_xor(mx, 1));
        mx = fmaxf(mx, __shfl_xor(mx, 2));
        mx = fmaxf(mx, __shfl_xor(mx, 4));
        float sum = 0.f;
        #pragma unroll 8
        for (int c = 0; c < 48; ++c) {
          float e = __expf(S[row][q * 48 + c] - mx);
          S[row][q * 48 + c] = e;
          sum += e;
        }
        sum += __shfl_xor(sum, 1);
        sum += __shfl_xor(sum, 2);
        sum += __shfl_xor(sum, 4);
        float inv = 1.0f / sum;
        #pragma unroll 8
        for (int c = 0; c < 48; ++c)
          P[row][q * 48 + c] = f2bf(S[row][q * 48 + c] * inv);
      }
      __syncthreads();
      if (wave < 2) {
        int ntd = wave;
        const unsigned short* bsrc = vt_bf + (size_t)(h * 64 + ntd * 32 + col) * 384 + half * 8;
        f32x16 acc = {};
        #pragma unroll
        for (int ks = 0; ks < 24; ++ks) {
          short8v a = *reinterpret_cast<const short8v*>(&P[col][ks * 16 + half * 8]);
          short8v b = *reinterpret_cast<const short8v*>(bsrc + ks * 16);
          acc = __builtin_amdgcn_mfma_f32_32x32x16_bf16(a, b, acc, 0, 0, 0);
        }
        #pragma unroll
        for (int reg = 0; reg < 16; ++reg)
          at_bf[(size_t)(n0 + MLROW(reg, half)) * 256 + h * 64 + ntd * 32 + col] =
              f2bf(acc[reg]);
      }
    }
    gsync(bar, ph++);

    // ---- stage Pj: proj = attno @ wo + bo (f32) ----
    for (int t = wid; t < 96; t += 192) {
      int mt = t % 12, nt = t / 12;
      const unsigned short* asrc = at_bf + (size_t)(mt * 32 + col) * 256 + half * 8;
      const unsigned short* bsrc = wo_fl + ((size_t)nt * 64 + lane) * 8;
      f32x16 acc = mfma_tile<16, 8>(asrc, bsrc);
      int n = nt * 32 + col;
      float bb = bo[n];
      #pragma unroll
      for (int reg = 0; reg < 16; ++reg)
        proj[(size_t)(mt * 32 + MLROW(reg, half)) * 256 + n] = acc[reg] + bb;
    }
    gsync(bar, ph++);

    // ---- stage L1: x = LN(x + proj), one row per wave ----
    {
      const float* g = ln1g + (size_t)l * 256;
      const float* be = ln1b + (size_t)l * 256;
      for (int row = wid; row < 384; row += 192) {
        float4 pr = reinterpret_cast<const float4*>(proj + (size_t)row * 256)[lane];
        float4 xr = reinterpret_cast<const float4*>(xbuf + (size_t)row * 256)[lane];
        float v0 = pr.x + xr.x, v1 = pr.y + xr.y, v2 = pr.z + xr.z, v3 = pr.w + xr.w;
        float s = v0 + v1 + v2 + v3;
        float s2 = v0 * v0 + v1 * v1 + v2 * v2 + v3 * v3;
        #pragma unroll
        for (int off = 1; off < 64; off <<= 1) {
          s += __shfl_xor(s, off);
          s2 += __shfl_xor(s2, off);
        }
        float mu = s * (1.0f / 256.0f);
        float var = s2 * (1.0f / 256.0f) - mu * mu;
        float inv = rsqrtf(var + 1e-5f);
        float4 g4 = reinterpret_cast<const float4*>(g)[lane];
        float4 b4 = reinterpret_cast<const float4*>(be)[lane];
        float o0 = (v0 - mu) * inv * g4.x + b4.x;
        float o1 = (v1 - mu) * inv * g4.y + b4.y;
        float o2 = (v2 - mu) * inv * g4.z + b4.z;
        float o3 = (v3 - mu) * inv * g4.w + b4.w;
        float4 o4 = make_float4(o0, o1, o2, o3);
        reinterpret_cast<float4*>(xbuf + (size_t)row * 256)[lane] = o4;
        uint2 pk;
        pk.x = cvt_pk_bf16(o0, o1);
        pk.y = cvt_pk_bf16(o2, o3);
        *reinterpret_cast<uint2*>(x_bf + (size_t)row * 256 + lane * 4) = pk;
      }
    }
    gsync(bar, ph++);

    // ---- stage F1: ffh = relu(x @ w1 + b1) (bf16) ----
    for (int t = wid; t < 384; t += 192) {
      int mt = t % 12, nt = t / 12;
      const unsigned short* asrc = x_bf + (size_t)(mt * 32 + col) * 256 + half * 8;
      const unsigned short* bsrc = fw1_fl + ((size_t)nt * 64 + lane) * 8;
      f32x16 acc = mfma_tile<16, 32>(asrc, bsrc);
      int n = nt * 32 + col;
      float bb = b1l[n];
      #pragma unroll
      for (int reg = 0; reg < 16; ++reg) {
        int row = mt * 32 + MLROW(reg, half);
        ffh_bf[(size_t)row * 1024 + n] = f2bf(fmaxf(acc[reg] + bb, 0.f));
      }
    }
    gsync(bar, ph++);

    // ---- stage F2: proj = ffh @ w2 + b2 (f32) ----
    for (int t = wid; t < 96; t += 192) {
      int mt = t % 12, nt = t / 12;
      const unsigned short* asrc = ffh_bf + (size_t)(mt * 32 + col) * 1024 + half * 8;
      const unsigned short* bsrc = fw2_fl + ((size_t)nt * 64 + lane) * 8;
      f32x16 acc = mfma_tile<64, 8>(asrc, bsrc);
      int n = nt * 32 + col;
      float bb = b2l[n];
      #pragma unroll
      for (int reg = 0; reg < 16; ++reg)
        proj[(size_t)(mt * 32 + MLROW(reg, half)) * 256 + n] = acc[reg] + bb;
    }
    gsync(bar, ph++);

    // ---- stage L2: x = LN(x + proj) ----
    {
      const float* g = ln2g + (size_t)l * 256;
      const float* be = ln2b + (size_t)l * 256;
      for (int row = wid; row < 384; row += 192) {
        float4 pr = reinterpret_cast<const float4*>(proj + (size_t)row * 256)[lane];
        float4 xr = reinterpret_cast<const float4*>(xbuf + (size_t)row * 256)[lane];
        float v0 = pr.x + xr.x, v1 = pr.y + xr.y, v2 = pr.z + xr.z, v3 = pr.w + xr.w;
        float s = v0 + v1 + v2 + v3;
        float s2 = v0 * v0 + v1 * v1 + v2 * v2 + v3 * v3;
        #pragma unroll
        for (int off = 1; off < 64; off <<= 1) {
          s += __shfl_xor(s, off);
          s2 += __shfl_xor(s2, off);
        }
        float mu = s * (1.0f / 256.0f);
        float var = s2 * (1.0f / 256.0f) - mu * mu;
        float inv = rsqrtf(var + 1e-5f);
        float4 g4 = reinterpret_cast<const float4*>(g)[lane];
        float4 b4 = reinterpret_cast<const float4*>(be)[lane];
        float o0 = (v0 - mu) * inv * g4.x + b4.x;
        float o1 = (v1 - mu) * inv * g4.y + b4.y;
        float o2 = (v2 - mu) * inv * g4.z + b4.z;
        float o3 = (v3 - mu) * inv * g4.w + b4.w;
        float4 o4 = make_float4(o0, o1, o2, o3);
        reinterpret_cast<float4*>(xbuf + (size_t)row * 256)[lane] = o4;
        uint2 pk;
        pk.x = cvt_pk_bf16(o0, o1);
        pk.y = cvt_pk_bf16(o2, o3);
        *reinterpret_cast<uint2*>(x_bf + (size_t)row * 256 + lane * 4) = pk;
      }
    }
    gsync(bar, ph++);
  }

  // ---- stage UV: U,V = x @ mw1 halves + box/bias epilogue ----
  for (int t = wid; t < 384; t += 192) {
    int z = t / 192, id = t % 192;
    int mt = id % 12, nt = id / 12;
    const unsigned short* asrc = x_bf + (size_t)(mt * 32 + col) * 256 + half * 8;
    const unsigned short* bsrc = mw1_f + (size_t)z * 131072 + ((size_t)nt * 64 + lane) * 8;
    f32x16 acc = mfma_tile<16, 16>(asrc, bsrc);
    int n = nt * 32 + col;
    float w0 = mw1[(size_t)(512 + z * 4 + 0) * HIDN + n];
    float w1r = mw1[(size_t)(512 + z * 4 + 1) * HIDN + n];
    float w2r = mw1[(size_t)(512 + z * 4 + 2) * HIDN + n];
    float w3 = mw1[(size_t)(512 + z * 4 + 3) * HIDN + n];
    float bb = (z == 0) ? mb1[n] : 0.f;
    #pragma unroll
    for (int reg = 0; reg < 16; ++reg) {
      int row = mt * 32 + MLROW(reg, half);
      const float* bx = boxes + row * 4;
      float v = acc[reg] + bb + bx[0] * w0 + bx[1] * w1r + bx[2] * w2r + bx[3] * w3;
      if (z == 0) U[(size_t)row * HIDN + n] = v;
      else        Vbf[(size_t)row * HIDN + n] = f2bf(v);
    }
  }
}

// ===== pair MLP (r13 v9, measured best 41us): LDS W2 + 2-i wave tasks ======
__global__ __launch_bounds__(512, 2)
void pair_mfma(const float* __restrict__ U, const unsigned short* __restrict__ Vbf,
               const unsigned short* __restrict__ w2frag,
               const float* __restrict__ b2, float* __restrict__ out) {
  __shared__ unsigned short w2l[32768];   // 64 KB
  #pragma unroll
  for (int p = 0; p < 8; ++p) {
    int off = p * 4096 + threadIdx.x * 8;
    *reinterpret_cast<uint4v*>(&w2l[off]) =
        *reinterpret_cast<const uint4v*>(w2frag + off);
  }
  __syncthreads();

  int wave = threadIdx.x >> 6, lane = threadIdx.x & 63;
  int task = blockIdx.x * 8 + wave;    // 0..2303
  int ip = task / 12, jt = task % 12;
  int i0 = ip * 2;
  int col = lane & 31, half = lane >> 5;
  int j_row = jt * 32 + col;

  const unsigned short* vsrc = Vbf + (size_t)j_row * HIDN + half * 8;
  const float* u0 = U + (size_t)i0 * HIDN + half * 8;
  const float* u1 = u0 + HIDN;
  const unsigned short* bsrc = w2l + (size_t)lane * 8;

  f32x16 acc00 = {}, acc01 = {}, acc10 = {}, acc11 = {};
  #pragma unroll
  for (int ks = 0; ks < 32; ++ks) {
    ushort8 v8 = *reinterpret_cast<const ushort8*>(vsrc + ks * 16);
    short8v b0 = *reinterpret_cast<const short8v*>(bsrc + (size_t)(ks * 2 + 0) * 512);
    short8v b1v = *reinterpret_cast<const short8v*>(bsrc + (size_t)(ks * 2 + 1) * 512);
    float4 ua0 = *reinterpret_cast<const float4*>(u0 + ks * 16);
    float4 ub0 = *reinterpret_cast<const float4*>(u0 + ks * 16 + 4);
    float4 ua1 = *reinterpret_cast<const float4*>(u1 + ks * 16);
    float4 ub1 = *reinterpret_cast<const float4*>(u1 + ks * 16 + 4);
    float v0 = bf2f(v8[0]), v1 = bf2f(v8[1]), v2 = bf2f(v8[2]), v3 = bf2f(v8[3]);
    float v4 = bf2f(v8[4]), v5 = bf2f(v8[5]), v6 = bf2f(v8[6]), v7 = bf2f(v8[7]);
    uint4v pk0;
    pk0[0] = cvt_pk_bf16(fmaxf(v0 + ua0.x, 0.f), fmaxf(v1 + ua0.y, 0.f));
    pk0[1] = cvt_pk_bf16(fmaxf(v2 + ua0.z, 0.f), fmaxf(v3 + ua0.w, 0.f));
    pk0[2] = cvt_pk_bf16(fmaxf(v4 + ub0.x, 0.f), fmaxf(v5 + ub0.y, 0.f));
    pk0[3] = cvt_pk_bf16(fmaxf(v6 + ub0.z, 0.f), fmaxf(v7 + ub0.w, 0.f));
    short8v a0 = *reinterpret_cast<short8v*>(&pk0);
    acc00 = __builtin_amdgcn_mfma_f32_32x32x16_bf16(a0, b0, acc00, 0, 0, 0);
    acc01 = __builtin_amdgcn_mfma_f32_32x32x16_bf16(a0, b1v, acc01, 0, 0, 0);
    uint4v pk1;
    pk1[0] = cvt_pk_bf16(fmaxf(v0 + ua1.x, 0.f), fmaxf(v1 + ua1.y, 0.f));
    pk1[1] = cvt_pk_bf16(fmaxf(v2 + ua1.z, 0.f), fmaxf(v3 + ua1.w, 0.f));
    pk1[2] = cvt_pk_bf16(fmaxf(v4 + ub1.x, 0.f), fmaxf(v5 + ub1.y, 0.f));
    pk1[3] = cvt_pk_bf16(fmaxf(v6 + ub1.z, 0.f), fmaxf(v7 + ub1.w, 0.f));
    short8v a1 = *reinterpret_cast<short8v*>(&pk1);
    acc10 = __builtin_amdgcn_mfma_f32_32x32x16_bf16(a1, b0, acc10, 0, 0, 0);
    acc11 = __builtin_amdgcn_mfma_f32_32x32x16_bf16(a1, b1v, acc11, 0, 0, 0);
  }

  float b2v0 = b2[col];
  float b2v1 = (32 + col < NCLS) ? b2[32 + col] : 0.f;
  float* lg = out + 2 * (size_t)NPAIR;
  int i1 = i0 + 1;
  #pragma unroll
  for (int reg = 0; reg < 16; ++reg) {
    int j = jt * 32 + MLROW(reg, half);
    if (j != i0) {
      int p = i0 * (NN - 1) + (j > i0 ? j - 1 : j);
      float* row = lg + (size_t)p * NCLS;
      row[col] = acc00[reg] + b2v0;
      if (col < NCLS - 32) row[32 + col] = acc01[reg] + b2v1;
    }
    if (j != i1) {
      int p = i1 * (NN - 1) + (j > i1 ? j - 1 : j);
      float* row = lg + (size_t)p * NCLS;
      row[col] = acc10[reg] + b2v0;
      if (col < NCLS - 32) row[32 + col] = acc11[reg] + b2v1;
    }
  }
}

// ===========================================================================
extern "C" void kernel_launch(void* const* d_in, const int* in_sizes, int n_in,
                              void* d_out, int out_size, void* d_ws, size_t ws_size,
                              hipStream_t stream) {
  const float* node   = (const float*)d_in[0];
  const float* boxes  = (const float*)d_in[1];
  const float* w_in   = (const float*)d_in[2];
  const float* b_in   = (const float*)d_in[3];
  const float* w_out  = (const float*)d_in[4];
  const float* b_out  = (const float*)d_in[5];
  const float* fw1    = (const float*)d_in[6];
  const float* fb1    = (const float*)d_in[7];
  const float* fw2    = (const float*)d_in[8];
  const float* fb2    = (const float*)d_in[9];
  const float* ln1g   = (const float*)d_in[10];
  const float* ln1b   = (const float*)d_in[11];
  const float* ln2g   = (const float*)d_in[12];
  const float* ln2b   = (const float*)d_in[13];
  const float* mw1    = (const float*)d_in[14];
  const float* mb1    = (const float*)d_in[15];
  const float* mw2    = (const float*)d_in[16];
  const float* mb2    = (const float*)d_in[17];
  float* out = (float*)d_out;

  float* ws = (float*)d_ws;
  float* xbuf = ws;                    // 98304 f32
  float* proj = xbuf + 98304;          // 98304 f32
  float* U    = proj + 98304;          // 196608 f32
  unsigned short* us = (unsigned short*)(U + 196608);
  unsigned short* x_bf   = us;             us += 98304;
  unsigned short* qk_bf  = us;             us += 196608;   // [384][512]
  unsigned short* vt_bf  = us;             us += 98304;    // [256][384]
  unsigned short* at_bf  = us;             us += 98304;    // [384][256]
  unsigned short* ffh_bf = us;             us += 393216;   // [384][1024]
  unsigned short* Vbf    = us;             us += 196608;   // [384][512]
  unsigned short* wi_f   = us;             us += 393216;   // 2 x 196608
  unsigned short* wo_f   = us;             us += 131072;   // 2 x 65536
  unsigned short* fw1_f  = us;             us += 524288;   // 2 x 262144
  unsigned short* fw2_f  = us;             us += 524288;   // 2 x 262144
  unsigned short* mw1_f  = us;             us += 262144;   // 2 x 131072
  unsigned short* w2_f   = us;             us += 32768;
  unsigned* bar = (unsigned*)us;           // 16 x 4B barrier counters

  hipMemsetAsync(bar, 0, 64, stream);
  fused_enc<<<dim3(NBLK), dim3(256), 0, stream>>>(
      node, boxes, w_in, b_in, w_out, b_out, fw1, fb1, fw2, fb2,
      ln1g, ln1b, ln2g, ln2b, mw1, mb1, mw2,
      xbuf, proj, U, x_bf, qk_bf, vt_bf, at_bf, ffh_bf, Vbf,
      wi_f, wo_f, fw1_f, fw2_f, mw1_f, w2_f, out, bar);
  pair_mfma<<<dim3(288), dim3(512), 0, stream>>>(U, Vbf, w2_f, mb2, out);
}

// Round 17
// 134.955 us; speedup vs baseline: 1.9299x; 1.9299x over previous
//
#include <hip/hip_runtime.h>

#define NN 384
#define DM 256
#define NH 4
#define FF 1024
#define HIDN 512
#define NCLS 56
#define NPAIR (NN*(NN-1))   // 147072

typedef __attribute__((ext_vector_type(8))) short short8v;
typedef __attribute__((ext_vector_type(4))) float f32x4;
typedef __attribute__((ext_vector_type(16))) float f32x16;
typedef __attribute__((ext_vector_type(8))) unsigned short ushort8;
typedef __attribute__((ext_vector_type(4))) unsigned int uint4v;

static __device__ __forceinline__ unsigned short f2bf(float f) {
  unsigned u = __float_as_uint(f);
  unsigned r = u + 0x7fff + ((u >> 16) & 1);   // RNE
  return (unsigned short)(r >> 16);
}
static __device__ __forceinline__ float bf2f(unsigned short v) {
  return __uint_as_float(((unsigned)v) << 16);
}
static __device__ __forceinline__ unsigned cvt_pk_bf16(float lo, float hi) {
  unsigned r;
  asm("v_cvt_pk_bf16_f32 %0, %1, %2" : "=v"(r) : "v"(lo), "v"(hi));
  return r;
}
// C/D row for 32x32x16 MFMA (v7-verified): ml = (reg&3)+8*(reg>>2)+4*half
#define MLROW(reg, half) (((reg) & 3) + 8 * ((reg) >> 2) + 4 * (half))

// ===== pack ALL weights into 32x32x16 B-fragment order (bf16) ==============
__global__ __launch_bounds__(256)
void pack_all(const float* __restrict__ wi, const float* __restrict__ wo,
              const float* __restrict__ w1, const float* __restrict__ w2,
              const float* __restrict__ mw1, const float* __restrict__ mw2,
              unsigned short* __restrict__ wi_f, unsigned short* __restrict__ wo_f,
              unsigned short* __restrict__ w1_f, unsigned short* __restrict__ w2_f,
              unsigned short* __restrict__ mw1_f, unsigned short* __restrict__ mw2_f) {
  int y = blockIdx.y, z = blockIdx.z;
  int t = blockIdx.x * 256 + threadIdx.x;
  const float* src; unsigned short* dst; int K, N; long sS, sD;
  switch (y) {
    case 0: src = wi;  dst = wi_f;  K = 256;  N = 768;  sS = 256L*768;  sD = 196608; break;
    case 1: src = wo;  dst = wo_f;  K = 256;  N = 256;  sS = 256L*256;  sD = 65536;  break;
    case 2: src = w1;  dst = w1_f;  K = 256;  N = 1024; sS = 256L*1024; sD = 262144; break;
    case 3: src = w2;  dst = w2_f;  K = 1024; N = 256;  sS = 1024L*256; sD = 262144; break;
    case 4: src = mw1; dst = mw1_f; K = 256;  N = 512;  sS = 256L*512;  sD = 131072; break;
    default: {   // mw2 [512,56] -> Nt=2 padded to 64 cols, ks=32
      if (z || t >= 4096) return;
      int l = t & 63, nt = (t >> 6) & 1, ks = t >> 7;
      int kb = ks * 16 + ((l >> 5) * 8), n = nt * 32 + (l & 31);
      #pragma unroll
      for (int r = 0; r < 8; ++r) {
        float v = (n < NCLS) ? mw2[(size_t)(kb + r) * NCLS + n] : 0.f;
        mw2_f[(size_t)t * 8 + r] = f2bf(v);
      }
      return;
    }
  }
  int Nt = N >> 5;
  int total = (K >> 4) * Nt * 64;
  if (t >= total) return;
  src += z * sS; dst += z * sD;
  int l = t & 63;
  int rem = t >> 6;
  int nt = rem % Nt, ks = rem / Nt;
  int kb = ks * 16 + ((l >> 5) * 8), n = nt * 32 + (l & 31);
  #pragma unroll
  for (int r = 0; r < 8; ++r)
    dst[(size_t)t * 8 + r] = f2bf(src[(size_t)(kb + r) * N + n]);
}

// ===== prep: x_init (vec4) + pair indices, one launch ======================
__global__ __launch_bounds__(256)
void prep_misc(const float* __restrict__ node, float* __restrict__ xbuf,
               unsigned short* __restrict__ xbf, float* __restrict__ out) {
  int t = blockIdx.x * 256 + threadIdx.x;
  if (t < 24576) {
    float4 v = reinterpret_cast<const float4*>(node)[t];
    reinterpret_cast<float4*>(xbuf)[t] = v;
    uint2 pk;
    pk.x = cvt_pk_bf16(v.x, v.y);
    pk.y = cvt_pk_bf16(v.z, v.w);
    *reinterpret_cast<uint2*>(xbf + (size_t)t * 4) = pk;
  } else {
    int p = t - 24576;
    if (p >= NPAIR) return;
    int i = p / (NN - 1);
    int r = p - i * (NN - 1);
    int j = r + (r >= i ? 1 : 0);
    out[2 * p + 0] = (float)i;
    out[2 * p + 1] = (float)j;
  }
}

// ===== QKV projection: x_bf @ wi + bi; writes QK row-major + V transposed ==
__global__ __launch_bounds__(128)
void qkv_mfma(const unsigned short* __restrict__ xbf, const unsigned short* __restrict__ wif,
              const float* __restrict__ bi, unsigned short* __restrict__ qk,
              unsigned short* __restrict__ vt) {
  int id = blockIdx.x * 2 + (threadIdx.x >> 6);   // 0..287 (12 mt x 24 nt)
  int lane = threadIdx.x & 63;
  int mt = id % 12, nt = id / 12;
  int col = lane & 31, half = lane >> 5;
  const unsigned short* asrc = xbf + (size_t)(mt * 32 + col) * 256 + half * 8;
  const unsigned short* bsrc = wif + ((size_t)nt * 64 + lane) * 8;
  f32x16 acc = {};
  #pragma unroll
  for (int ks = 0; ks < 16; ++ks) {
    short8v a = *reinterpret_cast<const short8v*>(asrc + ks * 16);
    short8v b = *reinterpret_cast<const short8v*>(bsrc + (size_t)ks * 24 * 512);
    acc = __builtin_amdgcn_mfma_f32_32x32x16_bf16(a, b, acc, 0, 0, 0);
  }
  int n = nt * 32 + col;
  float bb = bi[n];
  #pragma unroll
  for (int reg = 0; reg < 16; ++reg) {
    int row = mt * 32 + MLROW(reg, half);
    float v = acc[reg] + bb;
    if (n < 512) qk[(size_t)row * 512 + n] = f2bf(v);         // Q | K
    else         vt[(size_t)(n - 512) * 384 + row] = f2bf(v); // V^T [256][384]
  }
}

// ===== fused attention: 32-row tiles, 48 blocks ============================
__global__ __launch_bounds__(256)
void fused_attn(const unsigned short* __restrict__ qk, const unsigned short* __restrict__ vt,
                unsigned short* __restrict__ attno) {
  __shared__ float S[32][385];
  __shared__ unsigned short P[32][392];
  int n0 = blockIdx.x * 32;
  int h = blockIdx.y;
  int wave = threadIdx.x >> 6, lane = threadIdx.x & 63;
  int col = lane & 31, half = lane >> 5;
  {
    const unsigned short* asrc = qk + (size_t)(n0 + col) * 512 + h * 64 + half * 8;
    #pragma unroll
    for (int jj = 0; jj < 3; ++jj) {
      int ntk = wave * 3 + jj;
      const unsigned short* bsrc = qk + (size_t)(ntk * 32 + col) * 512 + 256 + h * 64 + half * 8;
      f32x16 acc = {};
      #pragma unroll
      for (int ks = 0; ks < 4; ++ks) {
        short8v a = *reinterpret_cast<const short8v*>(asrc + ks * 16);
        short8v b = *reinterpret_cast<const short8v*>(bsrc + ks * 16);
        acc = __builtin_amdgcn_mfma_f32_32x32x16_bf16(a, b, acc, 0, 0, 0);
      }
      #pragma unroll
      for (int reg = 0; reg < 16; ++reg)
        S[MLROW(reg, half)][ntk * 32 + col] = acc[reg] * 0.125f;
    }
  }
  __syncthreads();
  {
    int row = threadIdx.x >> 3, q = threadIdx.x & 7;
    float mx = -1e30f;
    #pragma unroll 8
    for (int c = 0; c < 48; ++c) mx = fmaxf(mx, S[row][q * 48 + c]);
    mx = fmaxf(mx, __shfl_xor(mx, 1));
    mx = fmaxf(mx, __shfl_xor(mx, 2));
    mx = fmaxf(mx, __shfl_xor(mx, 4));
    float sum = 0.f;
    #pragma unroll 8
    for (int c = 0; c < 48; ++c) {
      float e = __expf(S[row][q * 48 + c] - mx);
      S[row][q * 48 + c] = e;
      sum += e;
    }
    sum += __shfl_xor(sum, 1);
    sum += __shfl_xor(sum, 2);
    sum += __shfl_xor(sum, 4);
    float inv = 1.0f / sum;
    #pragma unroll 8
    for (int c = 0; c < 48; ++c)
      P[row][q * 48 + c] = f2bf(S[row][q * 48 + c] * inv);
  }
  __syncthreads();
  if (wave < 2) {
    int ntd = wave;
    const unsigned short* bsrc = vt + (size_t)(h * 64 + ntd * 32 + col) * 384 + half * 8;
    f32x16 acc = {};
    #pragma unroll
    for (int ks = 0; ks < 24; ++ks) {
      short8v a = *reinterpret_cast<const short8v*>(&P[col][ks * 16 + half * 8]);
      short8v b = *reinterpret_cast<const short8v*>(bsrc + ks * 16);
      acc = __builtin_amdgcn_mfma_f32_32x32x16_bf16(a, b, acc, 0, 0, 0);
    }
    #pragma unroll
    for (int reg = 0; reg < 16; ++reg)
      attno[(size_t)(n0 + MLROW(reg, half)) * 256 + h * 64 + ntd * 32 + col] =
          f2bf(acc[reg]);
  }
}

// ===== residual add + LayerNorm (one row per block); emits f32 + bf16 ======
__global__ __launch_bounds__(256)
void add_ln(float* __restrict__ x, unsigned short* __restrict__ xbf,
            const float* __restrict__ r,
            const float* __restrict__ g, const float* __restrict__ b) {
  int i = blockIdx.x, t = threadIdx.x;
  float v = x[(size_t)i * DM + t] + r[(size_t)i * DM + t];
  __shared__ float red[256];
  red[t] = v; __syncthreads();
  for (int s = 128; s > 0; s >>= 1) { if (t < s) red[t] += red[t + s]; __syncthreads(); }
  float mu = red[0] * (1.0f / DM); __syncthreads();
  float dv = v - mu;
  red[t] = dv * dv; __syncthreads();
  for (int s = 128; s > 0; s >>= 1) { if (t < s) red[t] += red[t + s]; __syncthreads(); }
  float var = red[0] * (1.0f / DM);
  float inv = rsqrtf(var + 1e-5f);
  float o = dv * inv * g[t] + b[t];
  x[(size_t)i * DM + t] = o;
  xbf[(size_t)i * DM + t] = f2bf(o);
}

// ===== generic MFMA GEMM, one wave per 32x32 tile ==========================
template<int OUT_BF16, int RELU, int NKS, int NT>
__global__ void mfma_gemm(const unsigned short* __restrict__ A, int lda, long sA,
               const unsigned short* __restrict__ Bfrag, long sB,
               const float* __restrict__ bias,
               float* __restrict__ Cf, unsigned short* __restrict__ Cb,
               int ldc, long sC, int Mt) {
  int id = blockIdx.x * (blockDim.x >> 6) + (threadIdx.x >> 6);
  if (id >= Mt * NT) return;
  int lane = threadIdx.x & 63;
  int mt = id % Mt, nt = id / Mt;
  int z = blockIdx.z;
  int col = lane & 31, half = lane >> 5;
  const unsigned short* asrc = A + z * sA + (size_t)(mt * 32 + col) * lda + half * 8;
  const unsigned short* bsrc = Bfrag + z * sB + ((size_t)nt * 64 + lane) * 8;
  f32x16 acc = {};
  #pragma unroll
  for (int ks = 0; ks < NKS; ++ks) {
    short8v a = *reinterpret_cast<const short8v*>(asrc + ks * 16);
    short8v b = *reinterpret_cast<const short8v*>(bsrc + (size_t)ks * NT * 512);
    acc = __builtin_amdgcn_mfma_f32_32x32x16_bf16(a, b, acc, 0, 0, 0);
  }
  int n = nt * 32 + col;
  float bb = bias ? bias[n] : 0.f;
  #pragma unroll
  for (int reg = 0; reg < 16; ++reg) {
    int row = mt * 32 + MLROW(reg, half);
    float v = acc[reg] + bb;
    if (RELU) v = fmaxf(v, 0.f);
    if (OUT_BF16) Cb[z * sC + (size_t)row * ldc + n] = f2bf(v);
    else          Cf[z * sC + (size_t)row * ldc + n] = v;
  }
}

// ===== UV GEMM with fused box/bias epilogue ================================
__global__ __launch_bounds__(128)
void uv_gemm(const unsigned short* __restrict__ xbf, const unsigned short* __restrict__ mw1f,
             const float* __restrict__ mw1, const float* __restrict__ b1,
             const float* __restrict__ boxes,
             float* __restrict__ U, unsigned short* __restrict__ Vbf) {
  int id = blockIdx.x * 2 + (threadIdx.x >> 6);   // 0..191 (12 mt x 16 nt)
  int lane = threadIdx.x & 63;
  int z = blockIdx.z;
  int mt = id % 12, nt = id / 12;
  int col = lane & 31, half = lane >> 5;
  const unsigned short* asrc = xbf + (size_t)(mt * 32 + col) * 256 + half * 8;
  const unsigned short* bsrc = mw1f + (size_t)z * 131072 + ((size_t)nt * 64 + lane) * 8;
  f32x16 acc = {};
  #pragma unroll
  for (int ks = 0; ks < 16; ++ks) {
    short8v a = *reinterpret_cast<const short8v*>(asrc + ks * 16);
    short8v b = *reinterpret_cast<const short8v*>(bsrc + (size_t)ks * 16 * 512);
    acc = __builtin_amdgcn_mfma_f32_32x32x16_bf16(a, b, acc, 0, 0, 0);
  }
  int n = nt * 32 + col;
  float w0 = mw1[(size_t)(512 + z * 4 + 0) * HIDN + n];
  float w1r = mw1[(size_t)(512 + z * 4 + 1) * HIDN + n];
  float w2r = mw1[(size_t)(512 + z * 4 + 2) * HIDN + n];
  float w3 = mw1[(size_t)(512 + z * 4 + 3) * HIDN + n];
  float bb = (z == 0) ? b1[n] : 0.f;
  #pragma unroll
  for (int reg = 0; reg < 16; ++reg) {
    int row = mt * 32 + MLROW(reg, half);
    const float* bx = boxes + row * 4;
    float v = acc[reg] + bb + bx[0] * w0 + bx[1] * w1r + bx[2] * w2r + bx[3] * w3;
    if (z == 0) U[(size_t)row * HIDN + n] = v;
    else        Vbf[(size_t)row * HIDN + n] = f2bf(v);
  }
}

// ===== pair MLP v9 (r13, measured best 41us): LDS W2 + 2-i wave tasks ======
__global__ __launch_bounds__(512, 2)
void pair_mfma(const float* __restrict__ U, const unsigned short* __restrict__ Vbf,
               const unsigned short* __restrict__ w2frag,
               const float* __restrict__ b2, float* __restrict__ out) {
  __shared__ unsigned short w2l[32768];   // 64 KB
  #pragma unroll
  for (int p = 0; p < 8; ++p) {
    int off = p * 4096 + threadIdx.x * 8;
    *reinterpret_cast<uint4v*>(&w2l[off]) =
        *reinterpret_cast<const uint4v*>(w2frag + off);
  }
  __syncthreads();

  int wave = threadIdx.x >> 6, lane = threadIdx.x & 63;
  int task = blockIdx.x * 8 + wave;    // 0..2303
  int ip = task / 12, jt = task % 12;
  int i0 = ip * 2;
  int col = lane & 31, half = lane >> 5;
  int j_row = jt * 32 + col;

  const unsigned short* vsrc = Vbf + (size_t)j_row * HIDN + half * 8;
  const float* u0 = U + (size_t)i0 * HIDN + half * 8;
  const float* u1 = u0 + HIDN;
  const unsigned short* bsrc = w2l + (size_t)lane * 8;

  f32x16 acc00 = {}, acc01 = {}, acc10 = {}, acc11 = {};
  #pragma unroll
  for (int ks = 0; ks < 32; ++ks) {
    ushort8 v8 = *reinterpret_cast<const ushort8*>(vsrc + ks * 16);
    short8v b0 = *reinterpret_cast<const short8v*>(bsrc + (size_t)(ks * 2 + 0) * 512);
    short8v b1v = *reinterpret_cast<const short8v*>(bsrc + (size_t)(ks * 2 + 1) * 512);
    float4 ua0 = *reinterpret_cast<const float4*>(u0 + ks * 16);
    float4 ub0 = *reinterpret_cast<const float4*>(u0 + ks * 16 + 4);
    float4 ua1 = *reinterpret_cast<const float4*>(u1 + ks * 16);
    float4 ub1 = *reinterpret_cast<const float4*>(u1 + ks * 16 + 4);
    float v0 = bf2f(v8[0]), v1 = bf2f(v8[1]), v2 = bf2f(v8[2]), v3 = bf2f(v8[3]);
    float v4 = bf2f(v8[4]), v5 = bf2f(v8[5]), v6 = bf2f(v8[6]), v7 = bf2f(v8[7]);
    uint4v pk0;
    pk0[0] = cvt_pk_bf16(fmaxf(v0 + ua0.x, 0.f), fmaxf(v1 + ua0.y, 0.f));
    pk0[1] = cvt_pk_bf16(fmaxf(v2 + ua0.z, 0.f), fmaxf(v3 + ua0.w, 0.f));
    pk0[2] = cvt_pk_bf16(fmaxf(v4 + ub0.x, 0.f), fmaxf(v5 + ub0.y, 0.f));
    pk0[3] = cvt_pk_bf16(fmaxf(v6 + ub0.z, 0.f), fmaxf(v7 + ub0.w, 0.f));
    short8v a0 = *reinterpret_cast<short8v*>(&pk0);
    acc00 = __builtin_amdgcn_mfma_f32_32x32x16_bf16(a0, b0, acc00, 0, 0, 0);
    acc01 = __builtin_amdgcn_mfma_f32_32x32x16_bf16(a0, b1v, acc01, 0, 0, 0);
    uint4v pk1;
    pk1[0] = cvt_pk_bf16(fmaxf(v0 + ua1.x, 0.f), fmaxf(v1 + ua1.y, 0.f));
    pk1[1] = cvt_pk_bf16(fmaxf(v2 + ua1.z, 0.f), fmaxf(v3 + ua1.w, 0.f));
    pk1[2] = cvt_pk_bf16(fmaxf(v4 + ub1.x, 0.f), fmaxf(v5 + ub1.y, 0.f));
    pk1[3] = cvt_pk_bf16(fmaxf(v6 + ub1.z, 0.f), fmaxf(v7 + ub1.w, 0.f));
    short8v a1 = *reinterpret_cast<short8v*>(&pk1);
    acc10 = __builtin_amdgcn_mfma_f32_32x32x16_bf16(a1, b0, acc10, 0, 0, 0);
    acc11 = __builtin_amdgcn_mfma_f32_32x32x16_bf16(a1, b1v, acc11, 0, 0, 0);
  }

  float b2v0 = b2[col];
  float b2v1 = (32 + col < NCLS) ? b2[32 + col] : 0.f;
  float* lg = out + 2 * (size_t)NPAIR;
  int i1 = i0 + 1;
  #pragma unroll
  for (int reg = 0; reg < 16; ++reg) {
    int j = jt * 32 + MLROW(reg, half);
    if (j != i0) {
      int p = i0 * (NN - 1) + (j > i0 ? j - 1 : j);
      float* row = lg + (size_t)p * NCLS;
      row[col] = acc00[reg] + b2v0;
      if (col < NCLS - 32) row[32 + col] = acc01[reg] + b2v1;
    }
    if (j != i1) {
      int p = i1 * (NN - 1) + (j > i1 ? j - 1 : j);
      float* row = lg + (size_t)p * NCLS;
      row[col] = acc10[reg] + b2v0;
      if (col < NCLS - 32) row[32 + col] = acc11[reg] + b2v1;
    }
  }
}

// ===========================================================================
extern "C" void kernel_launch(void* const* d_in, const int* in_sizes, int n_in,
                              void* d_out, int out_size, void* d_ws, size_t ws_size,
                              hipStream_t stream) {
  const float* node   = (const float*)d_in[0];
  const float* boxes  = (const float*)d_in[1];
  const float* w_in   = (const float*)d_in[2];
  const float* b_in   = (const float*)d_in[3];
  const float* w_out  = (const float*)d_in[4];
  const float* b_out  = (const float*)d_in[5];
  const float* fw1    = (const float*)d_in[6];
  const float* fb1    = (const float*)d_in[7];
  const float* fw2    = (const float*)d_in[8];
  const float* fb2    = (const float*)d_in[9];
  const float* ln1g   = (const float*)d_in[10];
  const float* ln1b   = (const float*)d_in[11];
  const float* ln2g   = (const float*)d_in[12];
  const float* ln2b   = (const float*)d_in[13];
  const float* mw1    = (const float*)d_in[14];
  const float* mb1    = (const float*)d_in[15];
  const float* mw2    = (const float*)d_in[16];
  const float* mb2    = (const float*)d_in[17];
  float* out = (float*)d_out;

  float* ws = (float*)d_ws;
  float* xbuf = ws;                    // 98304 f32
  float* proj = xbuf + 98304;          // 98304 f32
  float* U    = proj + 98304;          // 196608 f32
  unsigned short* us = (unsigned short*)(U + 196608);
  unsigned short* x_bf   = us;             us += 98304;
  unsigned short* qk_bf  = us;             us += 196608;   // [384][512]
  unsigned short* vt_bf  = us;             us += 98304;    // [256][384]
  unsigned short* at_bf  = us;             us += 98304;    // [384][256]
  unsigned short* ffh_bf = us;             us += 393216;   // [384][1024]
  unsigned short* Vbf    = us;             us += 196608;   // [384][512]
  unsigned short* wi_f   = us;             us += 393216;   // 2 x 196608
  unsigned short* wo_f   = us;             us += 131072;   // 2 x 65536
  unsigned short* fw1_f  = us;             us += 524288;   // 2 x 262144
  unsigned short* fw2_f  = us;             us += 524288;   // 2 x 262144
  unsigned short* mw1_f  = us;             us += 262144;   // 2 x 131072
  unsigned short* w2_f   = us;             us += 32768;

  // one-time prep (wide grids; r16 lesson: never starve latency-bound work)
  pack_all<<<dim3(128, 6, 2), 256, 0, stream>>>(w_in, w_out, fw1, fw2, mw1, mw2,
                                                wi_f, wo_f, fw1_f, fw2_f, mw1_f, w2_f);
  prep_misc<<<dim3((24576 + NPAIR + 255) / 256), 256, 0, stream>>>(node, xbuf, x_bf, out);

  for (int l = 0; l < 2; ++l) {
    qkv_mfma<<<dim3(144), 128, 0, stream>>>(x_bf, wi_f + (size_t)l * 196608,
                                            b_in + (size_t)l * 768, qk_bf, vt_bf);
    fused_attn<<<dim3(12, 4), 256, 0, stream>>>(qk_bf, vt_bf, at_bf);
    mfma_gemm<0, 0, 16, 8><<<dim3(48), 128, 0, stream>>>(
        at_bf, 256, 0, wo_f + (size_t)l * 65536, 0, b_out + (size_t)l * 256,
        proj, nullptr, 256, 0, 12);
    add_ln<<<dim3(NN), 256, 0, stream>>>(xbuf, x_bf, proj,
                                         ln1g + (size_t)l * 256, ln1b + (size_t)l * 256);
    mfma_gemm<1, 1, 16, 32><<<dim3(192), 128, 0, stream>>>(
        x_bf, 256, 0, fw1_f + (size_t)l * 262144, 0, fb1 + (size_t)l * 1024,
        nullptr, ffh_bf, 1024, 0, 12);
    mfma_gemm<0, 0, 64, 8><<<dim3(48), 128, 0, stream>>>(
        ffh_bf, 1024, 0, fw2_f + (size_t)l * 262144, 0, fb2 + (size_t)l * 256,
        proj, nullptr, 256, 0, 12);
    add_ln<<<dim3(NN), 256, 0, stream>>>(xbuf, x_bf, proj,
                                         ln2g + (size_t)l * 256, ln2b + (size_t)l * 256);
  }

  // relation head: fused UV GEMM (+box/bias epilogue), then pair GEMM
  uv_gemm<<<dim3(96, 1, 2), 128, 0, stream>>>(x_bf, mw1_f, mw1, mb1, boxes, U, Vbf);
  pair_mfma<<<dim3(288), 512, 0, stream>>>(U, Vbf, w2_f, mb2, out);
}